// Round 1
// baseline (196.382 us; speedup 1.0000x reference)
//
#include <hip/hip_runtime.h>

#define BC 4        // B*C = 2*2
#define HD 1025
#define WD 1024
#define KHALF 15
#define KWIN 31
#define CH 32       // outputs per thread along the sliding axis

// Odd-even transposition sort, 31 passes -> fully sorted. Setup only (amortized
// over CH outputs), ~465 min/max pairs.
__device__ __forceinline__ void sort31(float* win) {
#pragma unroll
    for (int pass = 0; pass < KWIN; ++pass) {
#pragma unroll
        for (int i = (pass & 1); i + 1 < KWIN; i += 2) {
            float a = win[i], b = win[i + 1];
            win[i] = fminf(a, b);
            win[i + 1] = fmaxf(a, b);
        }
    }
}

// Sorted sliding-window update: remove oldv (guaranteed present), insert newv.
// All indices static -> stays in VGPRs, branchless cndmask chains.
__device__ __forceinline__ void slide31(float* win, float oldv, float newv) {
    // remove: shift left starting at first element >= oldv (== oldv since present)
    bool f = false;
#pragma unroll
    for (int i = 0; i < KWIN - 1; ++i) {
        f = f | (win[i] >= oldv);
        win[i] = f ? win[i + 1] : win[i];
    }
    // insert newv into sorted win[0..29] -> win[0..30]
#pragma unroll
    for (int i = KWIN - 1; i >= 1; --i) {
        float below = win[i - 1];
        float at = (i <= KWIN - 2) ? win[i] : __builtin_inff();
        win[i] = (below > newv) ? below : ((at > newv) ? newv : at);
    }
    win[0] = (win[0] > newv) ? newv : win[0];
}

// Median along W (time) -> harm. One thread per (bc, h, chunk-of-32-w).
__global__ __launch_bounds__(256) void harm_kernel(const float* __restrict__ S,
                                                   float* __restrict__ harm) {
    const int CHUNKS = WD / CH;  // 32
    int t = blockIdx.x * blockDim.x + threadIdx.x;
    if (t >= BC * HD * CHUNKS) return;
    int chunk = t % CHUNKS;
    int rest = t / CHUNKS;
    const float* row = S + (size_t)rest * WD;
    float* orow = harm + (size_t)rest * WD;
    int w0 = chunk * CH;

    float win[KWIN];
#pragma unroll
    for (int j = 0; j < KWIN; ++j) {
        int p = w0 - KHALF + j;
        win[j] = (p >= 0 && p < WD) ? row[p] : 0.0f;
    }
    sort31(win);
    orow[w0] = win[15];
#pragma unroll 1
    for (int s = 1; s < CH; ++s) {
        int w = w0 + s;
        int pOld = w - KHALF - 1;
        int pNew = w + KHALF;
        float oldv = (pOld >= 0) ? row[pOld] : 0.0f;          // pOld < WD always
        float newv = (pNew < WD) ? row[pNew] : 0.0f;          // pNew >= 0 always
        slide31(win, oldv, newv);
        orow[w] = win[15];
    }
}

// Median along H (freq) + fused softmask + both outputs.
// lane dim = w -> all global traffic coalesced. Reads harm (phase-1 result)
// at idx then overwrites out0[idx] in the same thread (no cross-thread hazard).
__global__ __launch_bounds__(256) void perc_mask_kernel(const float* __restrict__ S,
                                                        const float* __restrict__ harm,
                                                        float* __restrict__ out0,
                                                        float* __restrict__ out1) {
    int w = blockIdx.x * blockDim.x + threadIdx.x;  // 0..1023
    int h0 = blockIdx.y * CH;
    int bc = blockIdx.z;
    if (w >= WD || h0 >= HD) return;
    const size_t planeoff = (size_t)bc * HD * WD;
    const float* base = S + planeoff;

    float win[KWIN];
#pragma unroll
    for (int j = 0; j < KWIN; ++j) {
        int p = h0 - KHALF + j;
        win[j] = (p >= 0 && p < HD) ? base[(size_t)p * WD + w] : 0.0f;
    }
    sort31(win);

    int hend = min(h0 + CH, HD);
#pragma unroll 1
    for (int h = h0; h < hend; ++h) {
        if (h > h0) {
            int pOld = h - KHALF - 1;
            int pNew = h + KHALF;
            float oldv = (pOld >= 0) ? base[(size_t)pOld * WD + w] : 0.0f;
            float newv = (pNew < HD) ? base[(size_t)pNew * WD + w] : 0.0f;
            slide31(win, oldv, newv);
        }
        float pmed = win[15];
        size_t idx = planeoff + (size_t)h * WD + w;
        float sv = base[(size_t)h * WD + w];
        float hm = harm[idx];
        float h2 = hm * hm;
        float p2 = pmed * pmed;
        float inv = 1.0f / (h2 + p2);
        out0[idx] = sv * h2 * inv;
        out1[idx] = sv * p2 * inv;
    }
}

extern "C" void kernel_launch(void* const* d_in, const int* in_sizes, int n_in,
                              void* d_out, int out_size, void* d_ws, size_t ws_size,
                              hipStream_t stream) {
    const float* S = (const float*)d_in[0];
    float* out = (float*)d_out;
    const size_t N = (size_t)BC * HD * WD;  // 4,198,400
    float* harm = out;          // phase-1 scratch, overwritten by out0 in phase 2
    float* out1 = out + N;

    int totalH = BC * HD * (WD / CH);  // 131,200 threads
    harm_kernel<<<(totalH + 255) / 256, 256, 0, stream>>>(S, harm);

    dim3 grid(WD / 256, (HD + CH - 1) / CH, BC);  // (4, 33, 4)
    perc_mask_kernel<<<grid, 256, 0, stream>>>(S, harm, out, out1);
}

// Round 2
// 147.483 us; speedup vs baseline: 1.3316x; 1.3316x over previous
//
#include <hip/hip_runtime.h>

#define BC 4        // B*C = 2*2
#define HD 1025
#define WD 1024
#define KHALF 15
#define KWIN 31
#define CH 16       // outputs per thread along the sliding axis
#define ROWS 4      // rows per block in harm_kernel
#define PITCH 1056  // 1024 + 32 pad floats (one pad per 32) -> <=2-way LDS conflicts

// padded LDS offset for a logical w in [0, 1024+)
__device__ __forceinline__ int lp(int w) { return w + (w >> 5); }

// Odd-even transposition sort, 31 passes -> fully sorted. Setup only
// (amortized over CH outputs), ~465 min/max pairs.
__device__ __forceinline__ void sort31(float* win) {
#pragma unroll
    for (int pass = 0; pass < KWIN; ++pass) {
#pragma unroll
        for (int i = (pass & 1); i + 1 < KWIN; i += 2) {
            float a = win[i], b = win[i + 1];
            win[i] = fminf(a, b);
            win[i + 1] = fmaxf(a, b);
        }
    }
}

// Sorted sliding-window update: remove oldv (guaranteed present), insert newv.
// win sorted ascending => (win[i] >= oldv) is MONOTONE in i, so the remove
// needs no prefix chain: 30 independent cmp+sel. Insert reads only pre-update
// values (descending loop) => also independent. Chain depth ~3, not ~60.
__device__ __forceinline__ void slide31(float* win, float oldv, float newv) {
#pragma unroll
    for (int i = 0; i < KWIN - 1; ++i) {
        win[i] = (win[i] >= oldv) ? win[i + 1] : win[i];
    }
#pragma unroll
    for (int i = KWIN - 1; i >= 1; --i) {
        float below = win[i - 1];
        float at = (i <= KWIN - 2) ? win[i] : __builtin_inff();
        win[i] = (below > newv) ? below : ((at > newv) ? newv : at);
    }
    win[0] = (win[0] > newv) ? newv : win[0];
}

// Median along W (time) -> harm. Block = 256 threads = 4 rows x 64 chunks of 16.
// All global traffic coalesced via LDS staging; sliding reads hit LDS only.
__global__ __launch_bounds__(256) void harm_kernel(const float* __restrict__ S,
                                                   float* __restrict__ harm) {
    __shared__ float lds[ROWS * PITCH];
    const int tid = threadIdx.x;
    const int plane = blockIdx.z;
    const int row0 = blockIdx.x * ROWS;

    // coalesced load: 4 rows x 1024 floats, 16 per thread
#pragma unroll
    for (int i = 0; i < 16; ++i) {
        int flat = tid + 256 * i;          // 0..4095
        int r = flat >> 10, w = flat & 1023;
        int gr = row0 + r;
        if (gr < HD)
            lds[r * PITCH + lp(w)] = S[((size_t)plane * HD + gr) * WD + w];
    }
    __syncthreads();

    const int r = tid >> 6;   // 0..3
    const int c = tid & 63;   // chunk 0..63
    const int gr = row0 + r;
    const bool active = (gr < HD);
    float out[CH];
    if (active) {
        const float* row = lds + r * PITCH;
        const int w0 = c * CH;
        float win[KWIN];
#pragma unroll
        for (int j = 0; j < KWIN; ++j) {
            int p = w0 - KHALF + j;
            win[j] = (p >= 0 && p < WD) ? row[lp(p)] : 0.0f;
        }
        sort31(win);
        out[0] = win[15];
#pragma unroll 1
        for (int s = 1; s < CH; ++s) {
            int pOld = w0 + s - KHALF - 1;       // >= -15, < WD always
            int pNew = w0 + s + KHALF;           // >= 0, may be >= WD
            float oldv = (pOld >= 0) ? row[lp(pOld)] : 0.0f;
            float newv = (pNew < WD) ? row[lp(pNew)] : 0.0f;
            slide31(win, oldv, newv);
            out[s] = win[15];
        }
    }
    __syncthreads();  // input LDS no longer needed; reuse for output staging
    if (active) {
#pragma unroll
        for (int s = 0; s < CH; ++s)
            lds[r * PITCH + lp(c * CH + s)] = out[s];
    }
    __syncthreads();

    // coalesced store
#pragma unroll
    for (int i = 0; i < 16; ++i) {
        int flat = tid + 256 * i;
        int r2 = flat >> 10, w = flat & 1023;
        int gr2 = row0 + r2;
        if (gr2 < HD)
            harm[((size_t)plane * HD + gr2) * WD + w] = lds[r2 * PITCH + lp(w)];
    }
}

// Median along H (freq) + fused softmask + both outputs.
// lane dim = w -> all global traffic coalesced. Reads harm (phase-1 result)
// at idx then overwrites out0[idx] in the same thread (no cross-thread hazard).
__global__ __launch_bounds__(256) void perc_mask_kernel(const float* __restrict__ S,
                                                        const float* __restrict__ harm,
                                                        float* __restrict__ out0,
                                                        float* __restrict__ out1) {
    int w = blockIdx.x * blockDim.x + threadIdx.x;  // 0..1023
    int h0 = blockIdx.y * CH;
    int bc = blockIdx.z;
    if (w >= WD || h0 >= HD) return;
    const size_t planeoff = (size_t)bc * HD * WD;
    const float* base = S + planeoff;

    float win[KWIN];
#pragma unroll
    for (int j = 0; j < KWIN; ++j) {
        int p = h0 - KHALF + j;
        win[j] = (p >= 0 && p < HD) ? base[(size_t)p * WD + w] : 0.0f;
    }
    sort31(win);

    int hend = min(h0 + CH, HD);
#pragma unroll 1
    for (int h = h0; h < hend; ++h) {
        if (h > h0) {
            int pOld = h - KHALF - 1;
            int pNew = h + KHALF;
            float oldv = (pOld >= 0) ? base[(size_t)pOld * WD + w] : 0.0f;
            float newv = (pNew < HD) ? base[(size_t)pNew * WD + w] : 0.0f;
            slide31(win, oldv, newv);
        }
        float pmed = win[15];
        size_t idx = planeoff + (size_t)h * WD + w;
        float sv = base[(size_t)h * WD + w];
        float hm = harm[idx];
        float h2 = hm * hm;
        float p2 = pmed * pmed;
        float inv = 1.0f / (h2 + p2);
        out0[idx] = sv * h2 * inv;
        out1[idx] = sv * p2 * inv;
    }
}

extern "C" void kernel_launch(void* const* d_in, const int* in_sizes, int n_in,
                              void* d_out, int out_size, void* d_ws, size_t ws_size,
                              hipStream_t stream) {
    const float* S = (const float*)d_in[0];
    float* out = (float*)d_out;
    const size_t N = (size_t)BC * HD * WD;  // 4,198,400
    float* harm = out;          // phase-1 scratch, overwritten by out0 in phase 2
    float* out1 = out + N;

    dim3 hgrid((HD + ROWS - 1) / ROWS, 1, BC);  // (257, 1, 4)
    harm_kernel<<<hgrid, 256, 0, stream>>>(S, harm);

    dim3 pgrid(WD / 256, (HD + CH - 1) / CH, BC);  // (4, 65, 4)
    perc_mask_kernel<<<pgrid, 256, 0, stream>>>(S, harm, out, out1);
}

// Round 3
// 100.704 us; speedup vs baseline: 1.9501x; 1.4645x over previous
//
#include <hip/hip_runtime.h>

#define BC 4
#define HD 1025
#define WD 1024
#define KWIN 31
#define CH 8        // outputs per thread along the sliding axis

__device__ __forceinline__ void ce(float& x, float& y) {
    float lo = fminf(x, y);
    float hi = fmaxf(x, y);
    x = lo; y = hi;
}

// Batcher merge-exchange (Knuth 5.2.2M), N=31, t=5: 186 compare-exchanges,
// ~2.5x cheaper than odd-even transposition. All bounds compile-time.
__device__ __forceinline__ void sort31(float* a) {
#pragma unroll
    for (int pk = 4; pk >= 0; --pk) {
        const int p = 1 << pk;
#pragma unroll
        for (int k = 0; k <= 4 - pk; ++k) {
            const int d = (k == 0) ? p : ((16 >> (k - 1)) - p);
            const int r = (k == 0) ? 0 : p;
#pragma unroll
            for (int i = 0; i < KWIN - d; ++i)
                if ((i & p) == r) ce(a[i], a[i + d]);
        }
    }
}

// Sorted-window slide: remove oldv (guaranteed present), insert newv.
// Remove: monotone predicate -> 30 independent cmp+sel.
// Insert: pure min/max network b[i] = max(min(r[i], v), r[i-1]) -> 61 ops.
// ~121 VALU ops total, chain depth ~3.
__device__ __forceinline__ float slide_med(float* win, float oldv, float newv) {
    float r[KWIN - 1];
#pragma unroll
    for (int i = 0; i < KWIN - 1; ++i)
        r[i] = (win[i] >= oldv) ? win[i + 1] : win[i];
    win[0] = fminf(r[0], newv);
#pragma unroll
    for (int i = 1; i < KWIN - 1; ++i)
        win[i] = fmaxf(fminf(r[i], newv), r[i - 1]);
    win[KWIN - 1] = fmaxf(newv, r[KWIN - 2]);
    return win[15];
}

// XOR swizzle on 16B units: balances both coalesced (unit=lane) and
// lane-private (unit=2*lane+k) access patterns to the hw-minimum 8-way.
__device__ __forceinline__ float* swz(float* base, int f /* float idx, %4==0 */) {
    int u = f >> 2;
    u ^= (u >> 3) & 7;
    return base + (u << 2);
}

// Median along W. One wave per half-row (512 outputs, 8/lane), wave-private
// LDS segment; span preloaded to registers -> compute loop is pure VALU.
__global__ __launch_bounds__(256, 4) void harm_kernel(const float* __restrict__ S,
                                                      float* __restrict__ harm) {
    __shared__ float lds[4 * 544];
    const int tid = threadIdx.x;
    const int wv = tid >> 6, ln = tid & 63;
    const int hr = blockIdx.x * 4 + wv;      // half-row id
    const int plane = blockIdx.z;
    const int row = hr >> 1, half = hr & 1;
    const bool rowok = (row < HD);
    float* wl = lds + wv * 544;
    const float* rowg = S + ((size_t)plane * HD + row) * WD;
    const int hw0 = half * 512;
    const int g0 = hw0 - 16;                 // staged region start (16-aligned)

    if (rowok) {
#pragma unroll
        for (int it = 0; it < 3; ++it) {
            int t = 4 * ln + 256 * it;       // float idx in 544-float region
            if (t < 544) {
                int g = g0 + t;
                float4 v;
                if (g >= 0 && g + 3 < WD) {
                    v = *(const float4*)(rowg + g);
                } else {
                    v.x = ((unsigned)(g + 0) < WD) ? rowg[g + 0] : 0.f;
                    v.y = ((unsigned)(g + 1) < WD) ? rowg[g + 1] : 0.f;
                    v.z = ((unsigned)(g + 2) < WD) ? rowg[g + 2] : 0.f;
                    v.w = ((unsigned)(g + 3) < WD) ? rowg[g + 3] : 0.f;
                }
                *(float4*)swz(wl, t) = v;
            }
        }
    }
    __syncthreads();

    float med[CH];
    if (rowok) {
        float raw[40];                        // covers w in [w0-16, w0+24)
#pragma unroll
        for (int k = 0; k < 10; ++k) {
            float4 v = *(const float4*)swz(wl, 8 * ln + 4 * k);
            raw[4 * k + 0] = v.x; raw[4 * k + 1] = v.y;
            raw[4 * k + 2] = v.z; raw[4 * k + 3] = v.w;
        }
        float win[KWIN];
#pragma unroll
        for (int j = 0; j < KWIN; ++j) win[j] = raw[1 + j];   // w0-15..w0+15
        sort31(win);
        med[0] = win[15];
#pragma unroll
        for (int s = 1; s < CH; ++s)
            med[s] = slide_med(win, raw[s] /* w0+s-16 */, raw[s + 31] /* w0+s+15 */);
    }
    __syncthreads();   // region reused for output staging
    if (rowok) {
        *(float4*)swz(wl, 8 * ln)     = make_float4(med[0], med[1], med[2], med[3]);
        *(float4*)swz(wl, 8 * ln + 4) = make_float4(med[4], med[5], med[6], med[7]);
    }
    __syncthreads();
    if (rowok) {
        float* hrow = harm + ((size_t)plane * HD + row) * WD + hw0;
        float4 a = *(const float4*)swz(wl, 4 * ln);
        float4 b = *(const float4*)swz(wl, 256 + 4 * ln);
        *(float4*)(hrow + 4 * ln) = a;
        *(float4*)(hrow + 256 + 4 * ln) = b;
    }
}

// Median along H + fused softmask. Span of 38 rows preloaded to registers
// (coalesced, lane = w); compute loop is pure VALU; all stores coalesced.
__global__ __launch_bounds__(256, 4) void perc_mask_kernel(const float* __restrict__ S,
                                                           const float* __restrict__ harm,
                                                           float* __restrict__ out0,
                                                           float* __restrict__ out1) {
    const int w = blockIdx.x * 256 + threadIdx.x;   // 0..1023
    const int h0 = blockIdx.y * CH;
    const int plane = blockIdx.z;
    const size_t poff = (size_t)plane * HD * WD;
    const float* base = S + poff;

    float span[38];                                  // rows h0-15 .. h0+22
#pragma unroll
    for (int j = 0; j < 38; ++j) {
        int h = h0 - 15 + j;
        span[j] = ((unsigned)h < (unsigned)HD) ? base[(size_t)h * WD + w] : 0.f;
    }
    float hm[CH];
#pragma unroll
    for (int s = 0; s < CH; ++s) {
        int h = h0 + s;
        hm[s] = (h < HD) ? harm[poff + (size_t)h * WD + w] : 0.f;
    }

    float win[KWIN];
#pragma unroll
    for (int j = 0; j < KWIN; ++j) win[j] = span[j];
    sort31(win);

#pragma unroll
    for (int s = 0; s < CH; ++s) {
        int h = h0 + s;
        if (h >= HD) break;                          // block-uniform
        float pm = (s == 0) ? win[15] : slide_med(win, span[s - 1], span[s + 30]);
        float sv = span[15 + s];
        float h2 = hm[s] * hm[s];
        float p2 = pm * pm;
        float inv = 1.0f / (h2 + p2);
        size_t idx = poff + (size_t)h * WD + w;
        out0[idx] = sv * h2 * inv;
        out1[idx] = sv * p2 * inv;
    }
}

extern "C" void kernel_launch(void* const* d_in, const int* in_sizes, int n_in,
                              void* d_out, int out_size, void* d_ws, size_t ws_size,
                              hipStream_t stream) {
    const float* S = (const float*)d_in[0];
    float* out = (float*)d_out;
    const size_t N = (size_t)BC * HD * WD;  // 4,198,400
    float* harm = out;          // phase-1 scratch, overwritten by out0 in phase 2
    float* out1 = out + N;

    const int halfrows = HD * 2;                       // 2050 per plane
    dim3 hgrid((halfrows + 3) / 4, 1, BC);             // (513, 1, 4)
    harm_kernel<<<hgrid, 256, 0, stream>>>(S, harm);

    dim3 pgrid(WD / 256, (HD + CH - 1) / CH, BC);      // (4, 129, 4)
    perc_mask_kernel<<<pgrid, 256, 0, stream>>>(S, harm, out, out1);
}

// Round 4
// 100.183 us; speedup vs baseline: 1.9602x; 1.0052x over previous
//
#include <hip/hip_runtime.h>

#define BC 4
#define HD 1025
#define WD 1024
#define KWIN 31
#define HCH 16      // outputs per lane, harm (one wave per full row)
#define PCH 8       // outputs per thread, perc
#define REG 1056    // floats per wave-private LDS region in harm: [-16, 1040)

__device__ __forceinline__ void ce(float& x, float& y) {
    float lo = fminf(x, y);
    float hi = fmaxf(x, y);
    x = lo; y = hi;
}

// Batcher merge-exchange (Knuth 5.2.2M), N=31: 186 compare-exchanges.
__device__ __forceinline__ void sort31(float* a) {
#pragma unroll
    for (int pk = 4; pk >= 0; --pk) {
        const int p = 1 << pk;
#pragma unroll
        for (int k = 0; k <= 4 - pk; ++k) {
            const int d = (k == 0) ? p : ((16 >> (k - 1)) - p);
            const int r = (k == 0) ? 0 : p;
#pragma unroll
            for (int i = 0; i < KWIN - d; ++i)
                if ((i & p) == r) ce(a[i], a[i + d]);
        }
    }
}

// Sorted sliding-window update, fully in place (no r[] array -> -28 VGPR).
// Remove: monotone predicate (oldv present, win sorted) -> carried r_cur.
// Insert: v_med3_f32: new[i] = med3(newv, r[i-1], r[i]).  ~93 VALU, depth ~3.
__device__ __forceinline__ float slide_med(float* win, float oldv, float newv) {
    float rp = (win[0] >= oldv) ? win[1] : win[0];        // r[0]
    win[0] = fminf(rp, newv);
#pragma unroll
    for (int i = 1; i < KWIN - 1; ++i) {
        float rc = (win[i] >= oldv) ? win[i + 1] : win[i]; // r[i] (pre-update vals)
        win[i] = __builtin_amdgcn_fmed3f(newv, rp, rc);
        rp = rc;
    }
    win[KWIN - 1] = fmaxf(newv, rp);
    return win[15];
}

// XOR swizzle on 16B units: makes both coalesced (unit=lane+64*it) and
// lane-private (unit=4*lane+k) b128 access hit the structural-minimum 8 phases.
__device__ __forceinline__ float* swz(float* base, int f /* float idx, %4==0 */) {
    int u = f >> 2;
    u ^= (u >> 3) & 7;
    return base + (u << 2);
}

// Median along W. One wave per row (1024 outputs, 16/lane), wave-private LDS
// segment, NO block barriers (span preloaded to regs before any LDS reuse).
__global__ __launch_bounds__(256, 4) void harm_kernel(const float* __restrict__ S,
                                                      float* __restrict__ harm) {
    __shared__ float lds[4 * REG];
    const int tid = threadIdx.x;
    const int wv = tid >> 6, ln = tid & 63;
    const int row = blockIdx.x * 4 + wv;
    const int plane = blockIdx.z;
    const bool rowok = (row < HD);
    float* wl = lds + wv * REG;
    const float* rowg = S + ((size_t)plane * HD + row) * WD;

    if (rowok) {
        // stage floats for w in [-16, 1040): region idx t = w + 16
#pragma unroll
        for (int it = 0; it < 5; ++it) {
            int t = 4 * ln + 256 * it;
            if (t < REG) {
                int g = t - 16;
                float4 v;
                if (g >= 0 && g + 3 < WD) {
                    v = *(const float4*)(rowg + g);
                } else {
                    v.x = ((unsigned)(g + 0) < WD) ? rowg[g + 0] : 0.f;
                    v.y = ((unsigned)(g + 1) < WD) ? rowg[g + 1] : 0.f;
                    v.z = ((unsigned)(g + 2) < WD) ? rowg[g + 2] : 0.f;
                    v.w = ((unsigned)(g + 3) < WD) ? rowg[g + 3] : 0.f;
                }
                *(float4*)swz(wl, t) = v;
            }
        }
    }
    __builtin_amdgcn_wave_barrier();

    float m[HCH];
    if (rowok) {
        // preload full span to registers: w in [w0-16, w0+32), w0 = 16*ln
        float raw[48];
#pragma unroll
        for (int k = 0; k < 12; ++k) {
            float4 v = *(const float4*)swz(wl, 16 * ln + 4 * k);
            raw[4 * k + 0] = v.x; raw[4 * k + 1] = v.y;
            raw[4 * k + 2] = v.z; raw[4 * k + 3] = v.w;
        }
        float win[KWIN];
#pragma unroll
        for (int j = 0; j < KWIN; ++j) win[j] = raw[1 + j];   // w0-15 .. w0+15
        sort31(win);
        m[0] = win[15];
#pragma unroll
        for (int s = 1; s < HCH; ++s)
            m[s] = slide_med(win, raw[s] /* w0+s-16 */, raw[s + 31] /* w0+s+15 */);
    }
    __builtin_amdgcn_wave_barrier();   // input region dead (raw in regs) -> reuse
    if (rowok) {
#pragma unroll
        for (int g = 0; g < 4; ++g)
            *(float4*)swz(wl, 16 * ln + 4 * g) =
                make_float4(m[4 * g + 0], m[4 * g + 1], m[4 * g + 2], m[4 * g + 3]);
    }
    __builtin_amdgcn_wave_barrier();
    if (rowok) {
        float* hrow = harm + ((size_t)plane * HD + row) * WD;
#pragma unroll
        for (int it = 0; it < 4; ++it) {
            int t = 4 * ln + 256 * it;
            *(float4*)(hrow + t) = *(const float4*)swz(wl, t);
        }
    }
}

// Median along H + fused softmask. Span of 38 rows preloaded to registers
// (coalesced, lane = w); compute loop pure VALU; all stores coalesced.
__global__ __launch_bounds__(256, 4) void perc_mask_kernel(const float* __restrict__ S,
                                                           const float* __restrict__ harm,
                                                           float* __restrict__ out0,
                                                           float* __restrict__ out1) {
    const int w = blockIdx.x * 256 + threadIdx.x;   // 0..1023
    const int h0 = blockIdx.y * PCH;
    const int plane = blockIdx.z;
    const size_t poff = (size_t)plane * HD * WD;
    const float* base = S + poff;

    float span[38];                                  // rows h0-15 .. h0+22
#pragma unroll
    for (int j = 0; j < 38; ++j) {
        int h = h0 - 15 + j;
        span[j] = ((unsigned)h < (unsigned)HD) ? base[(size_t)h * WD + w] : 0.f;
    }

    float win[KWIN];
#pragma unroll
    for (int j = 0; j < KWIN; ++j) win[j] = span[j];
    sort31(win);

#pragma unroll
    for (int s = 0; s < PCH; ++s) {
        int h = h0 + s;
        if (h >= HD) break;                          // block-uniform
        float pm = (s == 0) ? win[15] : slide_med(win, span[s - 1], span[s + 30]);
        float sv = span[15 + s];
        size_t idx = poff + (size_t)h * WD + w;
        float hmv = harm[idx];
        float h2 = hmv * hmv;
        float p2 = pm * pm;
        float inv = 1.0f / (h2 + p2);
        out0[idx] = sv * h2 * inv;
        out1[idx] = sv * p2 * inv;
    }
}

extern "C" void kernel_launch(void* const* d_in, const int* in_sizes, int n_in,
                              void* d_out, int out_size, void* d_ws, size_t ws_size,
                              hipStream_t stream) {
    const float* S = (const float*)d_in[0];
    float* out = (float*)d_out;
    const size_t N = (size_t)BC * HD * WD;  // 4,198,400
    float* harm = out;          // phase-1 scratch, overwritten by out0 in phase 2
    float* out1 = out + N;

    dim3 hgrid((HD + 3) / 4, 1, BC);                   // (257, 1, 4)
    harm_kernel<<<hgrid, 256, 0, stream>>>(S, harm);

    dim3 pgrid(WD / 256, (HD + PCH - 1) / PCH, BC);    // (4, 129, 4)
    perc_mask_kernel<<<pgrid, 256, 0, stream>>>(S, harm, out, out1);
}